// Round 12
// baseline (2812.723 us; speedup 1.0000x reference)
//
#include <hip/hip_runtime.h>
#include <cstdint>
#include <cstddef>

#define BATCH  128
#define SEQT   512
#define EMB_D  300
#define VOCABN 5000
#define KP0    320
#define NU0    256
#define NU1    512
#define NU2    256
#define NDENSE 64
#define RING   32
#define LIM    (1 << 19)

typedef unsigned short ushortT;
typedef unsigned long long ull;
typedef __attribute__((ext_vector_type(8))) short bf16x8;
typedef __attribute__((ext_vector_type(8))) unsigned short u16x8;
typedef __attribute__((ext_vector_type(4))) unsigned short u16x4;
typedef __attribute__((ext_vector_type(4))) float f32x4;

#define AGT __HIP_MEMORY_SCOPE_AGENT

static __device__ __forceinline__ unsigned short f2bf(float x) {
    union { float f; unsigned u; } v; v.f = x;
    const unsigned r = v.u + 0x7FFFu + ((v.u >> 16) & 1u);
    return (unsigned short)(r >> 16);
}
static __device__ __forceinline__ float bf2f(unsigned short b) {
    union { unsigned u; float f; } v; v.u = ((unsigned)b) << 16;
    return v.f;
}
static __device__ __forceinline__ float sigmoidf_(float x) {
    return 1.f / (1.f + __expf(-x));
}
static __device__ __forceinline__ unsigned ald(const unsigned* p) {
    return __hip_atomic_load((unsigned*)p, __ATOMIC_RELAXED, AGT);
}
static __device__ __forceinline__ void ast(unsigned* p, unsigned v) {
    __hip_atomic_store(p, v, __ATOMIC_RELAXED, AGT);
}
// ---- coherent wide VMEM (device-scope, coalescing, no L2 flush) ----
static __device__ __forceinline__ void ld16c(u16x8* d, const void* p) {
    asm volatile("global_load_dwordx4 %0, %1, off sc0 sc1"
                 : "=&v"(*d) : "v"(p) : "memory");
}
static __device__ __forceinline__ void ld8c(u16x4* d, const void* p) {
    asm volatile("global_load_dwordx2 %0, %1, off sc0 sc1"
                 : "=&v"(*d) : "v"(p) : "memory");
}
static __device__ __forceinline__ void st4c(void* p, unsigned v) {
    asm volatile("global_store_dword %0, %1, off sc0 sc1"
                 :: "v"(p), "v"(v) : "memory");
}
static __device__ __forceinline__ void wait0() {
    asm volatile("s_waitcnt vmcnt(0)" ::: "memory");
    __builtin_amdgcn_sched_barrier(0);
}
static __device__ __forceinline__ void wait1() {
    asm volatile("s_waitcnt vmcnt(1)" ::: "memory");
    __builtin_amdgcn_sched_barrier(0);
}

// ---------------------------------------------------------------------------
// One-time converts
// ---------------------------------------------------------------------------
__global__ __launch_bounds__(256) void convert_WT(
    const float* __restrict__ W, ushortT* __restrict__ WbfT,
    int K, int NG, int KP, int total)
{
    for (int idx = blockIdx.x * 256 + threadIdx.x; idx < total; idx += gridDim.x * 256) {
        const int m = idx / KP, k = idx - m * KP;
        WbfT[idx] = (k < K) ? f2bf(W[(size_t)k * NG + m]) : (ushortT)0;
    }
}
__global__ __launch_bounds__(256) void convert_emb(
    const float* __restrict__ emb, ushortT* __restrict__ embbf)
{
    const int total = VOCABN * KP0;
    for (int idx = blockIdx.x * 256 + threadIdx.x; idx < total; idx += gridDim.x * 256) {
        const int v = idx / KP0, k = idx - v * KP0;
        embbf[idx] = (k < EMB_D) ? f2bf(emb[(size_t)v * EMB_D + k]) : (ushortT)0;
    }
}

// ---------------------------------------------------------------------------
// Precompute ALL of xg0: xg0[t][g][m][b16] bf16 (no recurrence dependency).
// ---------------------------------------------------------------------------
__global__ __launch_bounds__(256) void gemm_xg0(
    const ushortT* __restrict__ embbf,
    const int*   __restrict__ tokens,
    const ushortT* __restrict__ W0T,     // [1024][KP0]
    const float* __restrict__ bias,
    ushortT* __restrict__ xg0)           // [512][8][1024][16]
{
    __shared__ ushortT Wl[128][32];
    __shared__ ushortT Xl[128][32];
    __shared__ int tokL[128];

    const int tid = threadIdx.x;
    const int t   = blockIdx.x;
    const int m0  = blockIdx.y * 128;
    const int wv  = tid >> 6;
    const int lane = tid & 63;
    const int lo  = lane & 15;
    const int hi  = lane >> 4;

    if (tid < 128) tokL[tid] = tokens[tid * SEQT + t];
    __syncthreads();

    f32x4 acc[2][8];
    #pragma unroll
    for (int s = 0; s < 2; ++s)
        #pragma unroll
        for (int n = 0; n < 8; ++n)
            acc[s][n] = f32x4{0.f, 0.f, 0.f, 0.f};

    for (int k0 = 0; k0 < KP0; k0 += 32) {
        #pragma unroll
        for (int it = 0; it < 2; ++it) {
            const int idx = tid + it * 256;
            const int row = idx >> 2, gq = idx & 3;
            const int gs  = gq ^ ((row >> 1) & 3);
            *(u16x8*)&Wl[row][gs * 8] =
                *(const u16x8*)(W0T + (size_t)(m0 + row) * KP0 + k0 + gq * 8);
            *(u16x8*)&Xl[row][gs * 8] =
                *(const u16x8*)(embbf + (size_t)tokL[row] * KP0 + k0 + gq * 8);
        }
        __syncthreads();

        bf16x8 bfr[8];
        #pragma unroll
        for (int n = 0; n < 8; ++n) {
            const int row = n * 16 + lo;
            bfr[n] = *(const bf16x8*)&Xl[row][(hi ^ ((row >> 1) & 3)) * 8];
        }
        #pragma unroll
        for (int s = 0; s < 2; ++s) {
            const int row = wv * 32 + s * 16 + lo;
            const bf16x8 a = *(const bf16x8*)&Wl[row][(hi ^ ((row >> 1) & 3)) * 8];
            #pragma unroll
            for (int n = 0; n < 8; ++n)
                acc[s][n] = __builtin_amdgcn_mfma_f32_16x16x32_bf16(a, bfr[n], acc[s][n], 0, 0, 0);
        }
        __syncthreads();
    }

    #pragma unroll
    for (int s = 0; s < 2; ++s)
        #pragma unroll
        for (int j = 0; j < 4; ++j) {
            const int m = m0 + wv * 32 + s * 16 + hi * 4 + j;
            const float bi = bias[m];
            #pragma unroll
            for (int n = 0; n < 8; ++n)
                xg0[(((size_t)t * 8 + n) * 1024 + m) * 16 + lo] = f2bf(acc[s][n][j] + bi);
        }
}

// ---------------------------------------------------------------------------
// Recurrence role (flushless, wide-coherent). Group grp = rid&7 owns 16 b
// rows; WG owns JCOLS h-cols x 4 gates. Per step: batch-issue coherent xg +
// h-stage loads -> one vmcnt(0) -> LDS write; MFMA; gate exchange; c-waves
// store h (coherent dword, coalesced over lanes), drain, release flag.
// ---------------------------------------------------------------------------
template<int U_, int JCOLS, bool XATOMIC>
__device__ void rec_role(
    int rid,
    const float* __restrict__ Umat,
    const ushortT* __restrict__ xgring, int xmask,
    ushortT* __restrict__ hring,
    unsigned* Fown,
    unsigned* Xown, int xph, int xmsh,
    unsigned* Xguard, int nGd,
    char* smem)
{
    constexpr int NGu   = 4 * U_;
    constexpr int WPG   = U_ / JCOLS;
    constexpr int JH    = JCOLS / 2;
    constexpr int TILES = JH / 16;
    constexpr int KT    = U_ / 32;
    constexpr int GR    = U_ / 8;
    constexpr int NLD   = (16 * GR) / 512;   // coherent 16B loads per thread

    ushortT* hstage = (ushortT*)smem;                    // [16][U]
    float*   ex     = (float*)(smem + 2 * 16 * U_);      // [3][2][JH][17]

    const int tid = threadIdx.x, w = tid >> 6, lane = tid & 63;
    const int lo = lane & 15, hi = lane >> 4;
    const int g4 = w & 3, chh = w >> 2;
    const int grp = rid & 7, wgj = rid >> 3;
    const int b0 = grp * 16, J = wgj * JCOLS;
    const size_t S = (size_t)128 * U_;

    int gc[TILES];
    #pragma unroll
    for (int tl = 0; tl < TILES; ++tl)
        gc[tl] = g4 * U_ + J + chh * JH + tl * 16 + lo;

    bf16x8 bfr[TILES][KT];
    #pragma unroll
    for (int tl = 0; tl < TILES; ++tl)
        #pragma unroll
        for (int kt = 0; kt < KT; ++kt) {
            const float* up = Umat + (size_t)(kt * 32 + hi * 8) * NGu + gc[tl];
            bf16x8 v;
            #pragma unroll
            for (int i = 0; i < 8; ++i) v[i] = (short)f2bf(up[(size_t)i * NGu]);
            bfr[tl][kt] = v;
        }

    float creg[TILES][4];
    #pragma unroll
    for (int tl = 0; tl < TILES; ++tl)
        #pragma unroll
        for (int r = 0; r < 4; ++r) creg[tl][r] = 0.f;

    for (int t = 0; t < SEQT; ++t) {
        if (w == 0) {
            if (t > 0) {   // critical: own-group h flags
                int guard = 0; bool ok;
                do {
                    bool pred = true;
                    if (lane < 2 * WPG)
                        pred = ((int)ald(&Fown[(grp * 2 * WPG + lane) * 16]) >= t);
                    ok = __all(pred);
                    if (!ok) __builtin_amdgcn_s_sleep(1);
                } while (!ok && ++guard < LIM);
            }
            {   // non-critical: xg ready + ring guard (throttled)
                int guard = 0; bool ok;
                do {
                    bool pred = true;
                    if (XATOMIC && lane < 4) {
                        const int mt = (lane * U_ + J) >> xmsh;
                        const int fi = mt * xph + (t & (xph - 1));
                        pred = ((int)ald(&Xown[fi * 16]) >= t + 1);
                    }
                    for (int i = lane; i < nGd; i += 64)
                        pred = pred && ((int)ald(&Xguard[i * 16]) >= t - (RING - 1));
                    ok = __all(pred);
                    if (!ok) __builtin_amdgcn_s_sleep(8);
                } while (!ok && ++guard < LIM);
            }
        }
        __syncthreads();   // B1: deps satisfied

        // ---- batch-issue coherent loads: xg (slab t) + h stage ----
        u16x4 xr[TILES];
        const size_t xb = (size_t)((t & xmask) * 8 + grp) * NGu;
        if (XATOMIC) {
            #pragma unroll
            for (int tl = 0; tl < TILES; ++tl)
                ld8c(&xr[tl], xgring + (xb + gc[tl]) * 16 + hi * 4);
        } else {
            #pragma unroll
            for (int tl = 0; tl < TILES; ++tl)
                xr[tl] = *(const u16x4*)(xgring + (xb + gc[tl]) * 16 + hi * 4);
        }
        u16x8 hr[NLD];
        int di[NLD];
        if (t > 0) {
            const ushortT* hsrc = hring + (size_t)((t - 1) & (RING - 1)) * S;
            #pragma unroll
            for (int q = 0; q < NLD; ++q) {
                const int i = tid + q * 512;
                const int row = i / GR, gi = i - row * GR;
                ld16c(&hr[q], hsrc + (size_t)(b0 + row) * U_ + gi * 8);
                di[q] = (row * GR + (gi ^ (row & 7))) * 8;
            }
        }
        if (XATOMIC || t > 0) wait0();
        if (t > 0) {
            #pragma unroll
            for (int q = 0; q < NLD; ++q)
                *(u16x8*)&hstage[di[q]] = hr[q];
        }
        __syncthreads();   // B2: h staged

        f32x4 acc[TILES];
        #pragma unroll
        for (int tl = 0; tl < TILES; ++tl) acc[tl] = f32x4{0.f, 0.f, 0.f, 0.f};
        if (t > 0) {
            #pragma unroll
            for (int kt = 0; kt < KT; ++kt) {
                const int gs = (kt * 4 + hi) ^ (lo & 7);
                const bf16x8 a = *(const bf16x8*)&hstage[(lo * GR + gs) * 8];
                #pragma unroll
                for (int tl = 0; tl < TILES; ++tl)
                    acc[tl] = __builtin_amdgcn_mfma_f32_16x16x32_bf16(a, bfr[tl][kt], acc[tl], 0, 0, 0);
            }
        }

        float p[TILES][4];
        #pragma unroll
        for (int tl = 0; tl < TILES; ++tl)
            #pragma unroll
            for (int r = 0; r < 4; ++r)
                p[tl][r] = acc[tl][r] + bf2f(xr[tl][r]);

        if (g4 != 2) {
            const int slot = (g4 == 3) ? 2 : g4;    // i->0, f->1, o->2
            #pragma unroll
            for (int tl = 0; tl < TILES; ++tl)
                #pragma unroll
                for (int r = 0; r < 4; ++r)
                    ex[((slot * 2 + chh) * JH + tl * 16 + lo) * 17 + hi * 4 + r] = sigmoidf_(p[tl][r]);
        }
        __syncthreads();   // B3: gates exchanged

        if (g4 == 2) {
            ushortT* hwr = hring + (size_t)(t & (RING - 1)) * S;
            #pragma unroll
            for (int tl = 0; tl < TILES; ++tl) {
                const int jh = tl * 16 + lo;
                const int j  = gc[tl] - 2 * U_;
                unsigned own[4], oth[4];
                #pragma unroll
                for (int r = 0; r < 4; ++r) {
                    const int row = hi * 4 + r;
                    const float i_ = ex[((0 * 2 + chh) * JH + jh) * 17 + row];
                    const float f_ = ex[((1 * 2 + chh) * JH + jh) * 17 + row];
                    const float o_ = ex[((2 * 2 + chh) * JH + jh) * 17 + row];
                    creg[tl][r] = f_ * creg[tl][r] + i_ * fmaxf(p[tl][r], 0.f);
                    const float hn = o_ * fmaxf(creg[tl][r], 0.f);
                    own[r] = (unsigned)f2bf(hn);
                }
                #pragma unroll
                for (int r = 0; r < 4; ++r)
                    oth[r] = (unsigned)__shfl_xor((int)own[r], 1);
                const int odd = lo & 1;
                const int rb = odd ? 2 : 0;
                const int je = j - odd;
                #pragma unroll
                for (int q = 0; q < 2; ++q) {
                    const int r = rb + q;
                    const unsigned pk = odd ? (oth[r] | (own[r] << 16))
                                            : (own[r] | (oth[r] << 16));
                    st4c(&hwr[(size_t)(b0 + hi * 4 + r) * U_ + je], pk);
                }
            }
            wait0();
            if (lane == 0)
                ast(&Fown[((grp * WPG + wgj) * 2 + chh) * 16], (unsigned)(t + 1));
        }
    }
}

// ---------------------------------------------------------------------------
// GEMM worker (flushless wide-coherent, P-phase): MC m-cols, W in LDS once,
// h slab via coherent dwordx4 with counted-vmcnt ping-pong k-pipeline,
// coalesced coherent dword xg stores. Throttled polls (s_sleep 32).
// ---------------------------------------------------------------------------
template<int MC, int NGATES, int KP, int P>
__device__ void worker_role(
    int mtile, int phase,
    const ushortT* __restrict__ WT,     // [NGATES][KP] bf16
    const float* __restrict__ bias,
    const ushortT* __restrict__ hring,  // [RING][128][KP]
    ushortT* __restrict__ xgring,       // [RING][8][NGATES][16]
    unsigned* Fup, int nUp,
    unsigned* Fguard, int nGd,
    unsigned* Xrel,
    char* smem)
{
    constexpr int GR2 = KP / 8;
    constexpr int NIT = KP / 32;
    constexpr int WR  = MC / 8;          // m-cols per wave
    constexpr int MT  = WR / 16;         // 16-col m-tiles per wave
    ushortT* Wl = (ushortT*)smem;                   // [MC][KP] swizzled granules
    ushortT* Xl = (ushortT*)(smem + (size_t)MC * KP * 2);   // 2 x [128][32]

    const int tid = threadIdx.x, w = tid >> 6, lane = tid & 63;
    const int lo = lane & 15, hi = lane >> 4;
    const int m0 = mtile * MC;
    const int row = tid >> 2, gq = tid & 3;
    const int gsx = gq ^ ((row >> 1) & 3);

    // stage W tile once (plain loads: read-only, pre-written)
    for (int i = tid; i < MC * GR2; i += 512) {
        const int r_ = i / GR2, gi = i - r_ * GR2;
        const int gs = gi ^ (r_ & 7);
        *(u16x8*)&Wl[(r_ * GR2 + gs) * 8] =
            *(const u16x8*)(WT + (size_t)(m0 + r_) * KP + gi * 8);
    }
    float bv[MT][4];
    #pragma unroll
    for (int mt = 0; mt < MT; ++mt)
        #pragma unroll
        for (int j = 0; j < 4; ++j)
            bv[mt][j] = bias[m0 + w * WR + mt * 16 + hi * 4 + j];
    __syncthreads();

    for (int t = phase; t < SEQT; t += P) {
        if (w == 0) {
            int guard = 0; bool ok;
            do {
                bool pred = true;
                for (int i = lane; i < nUp; i += 64)
                    pred = pred && ((int)ald(&Fup[i * 16]) >= t + 1);
                for (int i = lane; i < nGd; i += 64)
                    pred = pred && ((int)ald(&Fguard[i * 16]) >= t - (RING - 1));
                ok = __all(pred);
                if (!ok) __builtin_amdgcn_s_sleep(32);
            } while (!ok && ++guard < LIM);
        }
        __syncthreads();

        const ushortT* hslab = hring + (size_t)(t & (RING - 1)) * 128 * KP;

        f32x4 acc[MT][8];
        #pragma unroll
        for (int mt = 0; mt < MT; ++mt)
            #pragma unroll
            for (int nn = 0; nn < 8; ++nn) acc[mt][nn] = f32x4{0.f, 0.f, 0.f, 0.f};

        u16x8 Ra, Rb;
        ld16c(&Ra, hslab + (size_t)row * KP + gq * 8);
        #pragma unroll
        for (int it = 0; it < NIT; ++it) {
            const bool even = ((it & 1) == 0);
            if (it + 1 < NIT) {
                ld16c(even ? &Rb : &Ra, hslab + (size_t)row * KP + (it + 1) * 32 + gq * 8);
                wait1();
            } else {
                wait0();
            }
            ushortT* Xc = Xl + (it & 1) * (128 * 32);
            *(u16x8*)&Xc[row * 32 + gsx * 8] = even ? Ra : Rb;
            __syncthreads();
            const int k0 = it * 32;
            #pragma unroll
            for (int mt = 0; mt < MT; ++mt) {
                const int arow = w * WR + mt * 16 + lo;
                const int gsa = ((k0 >> 3) + hi) ^ (arow & 7);
                const bf16x8 a = *(const bf16x8*)&Wl[(arow * GR2 + gsa) * 8];
                #pragma unroll
                for (int nn = 0; nn < 8; ++nn) {
                    const int brow = nn * 16 + lo;
                    const bf16x8 b = *(const bf16x8*)&Xc[brow * 32 + (hi ^ ((brow >> 1) & 3)) * 8];
                    acc[mt][nn] = __builtin_amdgcn_mfma_f32_16x16x32_bf16(a, b, acc[mt][nn], 0, 0, 0);
                }
            }
            __syncthreads();
        }

        // packed epilogue: adjacent-b pairs -> coherent u32 stores (coalesced)
        const size_t slab = (size_t)(t & (RING - 1)) * 8;
        #pragma unroll
        for (int mt = 0; mt < MT; ++mt) {
            #pragma unroll
            for (int nn = 0; nn < 8; ++nn) {
                const int b = nn * 16 + lo;
                unsigned own[4], oth[4];
                #pragma unroll
                for (int j = 0; j < 4; ++j)
                    own[j] = (unsigned)f2bf(acc[mt][nn][j] + bv[mt][j]);
                #pragma unroll
                for (int j = 0; j < 4; ++j)
                    oth[j] = (unsigned)__shfl_xor((int)own[j], 1);
                const int odd = lo & 1;
                const int jb = odd ? 2 : 0;
                const int be = (b & 15) - odd;
                #pragma unroll
                for (int q = 0; q < 2; ++q) {
                    const int j = jb + q;
                    const int m = m0 + w * WR + mt * 16 + hi * 4 + j;
                    const unsigned pk = odd ? (oth[j] | (own[j] << 16))
                                            : (own[j] | (oth[j] << 16));
                    st4c(&xgring[((slab + nn) * NGATES + m) * 16 + be], pk);
                }
            }
        }
        wait0();
        __syncthreads();
        if (tid == 0)
            ast(Xrel, (unsigned)(t + 1));
    }
}

// ---------------------------------------------------------------------------
// Megakernel. Grid 192 x 512 thr, 1 WG/CU.
//  [0,16) L0  [16,80) L1  [80,96) L2  [96,160) G1 (8mt x 8ph)  [160,192) G2 (8mt x 4ph)
// ---------------------------------------------------------------------------
struct MegaArgs {
    const float *U0, *U1, *U2;
    const ushortT *W1T, *W2T;
    const float *b1, *b2;
    const ushortT* xg0;
    ushortT *xg1, *xg2;
    ushortT *h0r, *h1r, *h2r;
    unsigned *F0, *F1, *F2, *X1, *X2;
};

__global__ __launch_bounds__(512, 1) void mega(MegaArgs A)
{
    extern __shared__ char smem[];
    const int bid = blockIdx.x;
    if (bid < 16) {
        rec_role<NU0, 128, false>(bid, A.U0, A.xg0, 511, A.h0r, A.F0,
                                  nullptr, 1, 0, A.X1, 64, smem);
    } else if (bid < 80) {
        rec_role<NU1, 64, true>(bid - 16, A.U1, A.xg1, RING - 1, A.h1r, A.F1,
                                A.X1, 8, 8, A.X2, 32, smem);
    } else if (bid < 96) {
        rec_role<NU2, 128, true>(bid - 80, A.U2, A.xg2, RING - 1, A.h2r, A.F2,
                                 A.X2, 4, 7, nullptr, 0, smem);
    } else if (bid < 160) {
        const int wid = bid - 96;
        const int mt = wid & 7, ph = wid >> 3;     // 8 mtiles x 8 phases
        worker_role<256, 2048, 256, 8>(mt, ph, A.W1T, A.b1, A.h0r, A.xg1,
                                       A.F0, 32, A.F1, 128, A.X1 + (mt * 8 + ph) * 16, smem);
    } else {
        const int wid = bid - 160;
        const int mt = wid & 7, ph = wid >> 3;     // 8 mtiles x 4 phases
        worker_role<128, 1024, 512, 4>(mt, ph, A.W2T, A.b2, A.h1r, A.xg2,
                                       A.F1, 128, A.F2, 32, A.X2 + (mt * 4 + ph) * 16, smem);
    }
}

// ---------------------------------------------------------------------------
// Head
// ---------------------------------------------------------------------------
__global__ __launch_bounds__(64) void head_kernel(
    const ushortT* __restrict__ h2,
    const float* __restrict__ Wd,
    const float* __restrict__ bd,
    const float* __restrict__ Wc,
    const float* __restrict__ bc,
    float* __restrict__ out)
{
    const int b = blockIdx.x;
    const int j = threadIdx.x;
    float a = bd[j];
    const ushortT* hrow = h2 + (size_t)b * NU2;
    #pragma unroll 4
    for (int k = 0; k < NU2; ++k)
        a += bf2f(hrow[k]) * Wd[(size_t)k * NDENSE + j];
    a = fmaxf(a, 0.f) * Wc[j];
    #pragma unroll
    for (int off = 32; off > 0; off >>= 1)
        a += __shfl_down(a, off);
    if (j == 0)
        out[b] = 1.f / (1.f + expf(-(a + bc[0])));
}

// ---------------------------------------------------------------------------
extern "C" void kernel_launch(void* const* d_in, const int* in_sizes, int n_in,
                              void* d_out, int out_size, void* d_ws, size_t ws_size,
                              hipStream_t stream)
{
    const int*   tokens = (const int*)  d_in[0];
    const float* emb    = (const float*)d_in[1];
    const float* W0     = (const float*)d_in[2];
    const float* Ur0    = (const float*)d_in[3];
    const float* b0v    = (const float*)d_in[4];
    const float* W1     = (const float*)d_in[5];
    const float* Ur1    = (const float*)d_in[6];
    const float* b1v    = (const float*)d_in[7];
    const float* W2     = (const float*)d_in[8];
    const float* Ur2    = (const float*)d_in[9];
    const float* b2v    = (const float*)d_in[10];
    const float* Wd     = (const float*)d_in[11];
    const float* bd     = (const float*)d_in[12];
    const float* Wc     = (const float*)d_in[13];
    const float* bc     = (const float*)d_in[14];
    float* out = (float*)d_out;

    char* p = (char*)d_ws;
    auto alloc = [&](size_t bytes) -> char* {
        char* q = p; p += (bytes + 255) & ~(size_t)255; return q;
    };
    ushortT* xg0   = (ushortT*)alloc((size_t)SEQT * 8 * 1024 * 16 * 2);  // 128 MB
    ushortT* xg1   = (ushortT*)alloc((size_t)RING * 8 * 2048 * 16 * 2);  // 16 MB
    ushortT* xg2   = (ushortT*)alloc((size_t)RING * 8 * 1024 * 16 * 2);  // 8 MB
    ushortT* h0r   = (ushortT*)alloc((size_t)RING * 128 * NU0 * 2);      // 2 MB
    ushortT* h1r   = (ushortT*)alloc((size_t)RING * 128 * NU1 * 2);      // 4 MB
    ushortT* h2r   = (ushortT*)alloc((size_t)RING * 128 * NU2 * 2);      // 2 MB
    ushortT* W0T   = (ushortT*)alloc((size_t)1024 * KP0 * 2);
    ushortT* W1T   = (ushortT*)alloc((size_t)2048 * NU0 * 2);
    ushortT* W2T   = (ushortT*)alloc((size_t)1024 * NU1 * 2);
    ushortT* embbf = (ushortT*)alloc((size_t)VOCABN * KP0 * 2);
    unsigned* flg  = (unsigned*)alloc(32768);

    // flag partition (16-word stride)
    unsigned* F0 = flg;             // 32  (16 L0 WGs x 2 c-waves)
    unsigned* F1 = F0 + 32 * 16;    // 128 (64 L1 WGs x 2)
    unsigned* F2 = F1 + 128 * 16;   // 32  (16 L2 WGs x 2)
    unsigned* X1 = F2 + 32 * 16;    // 64  (8 G1 mtiles x 8 phases)
    unsigned* X2 = X1 + 64 * 16;    // 32  (8 G2 mtiles x 4 phases)

    hipMemsetAsync(flg, 0, 32768, stream);

    convert_WT<<<512, 256, 0, stream>>>(W0, W0T, EMB_D, 1024, KP0, 1024 * KP0);
    convert_WT<<<512, 256, 0, stream>>>(W1, W1T, NU0, 2048, NU0, 2048 * NU0);
    convert_WT<<<512, 256, 0, stream>>>(W2, W2T, NU1, 1024, NU1, 1024 * NU1);
    convert_emb<<<1024, 256, 0, stream>>>(emb, embbf);

    gemm_xg0<<<dim3(SEQT, 8), 256, 0, stream>>>(embbf, tokens, W0T, b0v, xg0);

    MegaArgs A;
    A.U0 = Ur0; A.U1 = Ur1; A.U2 = Ur2;
    A.W1T = W1T; A.W2T = W2T;
    A.b1 = b1v; A.b2 = b2v;
    A.xg0 = xg0; A.xg1 = xg1; A.xg2 = xg2;
    A.h0r = h0r; A.h1r = h1r; A.h2r = h2r;
    A.F0 = F0; A.F1 = F1; A.F2 = F2; A.X1 = X1; A.X2 = X2;

    void* args[] = {&A};
    // smem: worker = MC*KP*2 (131072) + 2*128*32*2 (16384) = 147456 (max role)
    hipLaunchCooperativeKernel((void*)mega, dim3(192), dim3(512), args, 147456, stream);

    // final h of layer 2 = ring slab (511 & 31) = 31
    head_kernel<<<BATCH, 64, 0, stream>>>(h2r + (size_t)31 * 128 * NU2,
                                          Wd, bd, Wc, bc, out);
}

// Round 13
// 2460.625 us; speedup vs baseline: 1.1431x; 1.1431x over previous
//
#include <hip/hip_runtime.h>
#include <cstdint>
#include <cstddef>

#define BATCH  128
#define SEQT   512
#define EMB_D  300
#define VOCABN 5000
#define KP0    320
#define NU0    256
#define NU1    512
#define NU2    256
#define NDENSE 64
#define RING   32
#define LIM    (1 << 19)

typedef unsigned short ushortT;
typedef unsigned long long ull;
typedef __attribute__((ext_vector_type(8))) short bf16x8;
typedef __attribute__((ext_vector_type(8))) unsigned short u16x8;
typedef __attribute__((ext_vector_type(4))) unsigned short u16x4;
typedef __attribute__((ext_vector_type(4))) float f32x4;

#define AGT __HIP_MEMORY_SCOPE_AGENT

static __device__ __forceinline__ unsigned short f2bf(float x) {
    union { float f; unsigned u; } v; v.f = x;
    const unsigned r = v.u + 0x7FFFu + ((v.u >> 16) & 1u);
    return (unsigned short)(r >> 16);
}
static __device__ __forceinline__ float bf2f(unsigned short b) {
    union { unsigned u; float f; } v; v.u = ((unsigned)b) << 16;
    return v.f;
}
static __device__ __forceinline__ float sigmoidf_(float x) {
    return 1.f / (1.f + __expf(-x));
}
static __device__ __forceinline__ unsigned ald(const unsigned* p) {
    return __hip_atomic_load((unsigned*)p, __ATOMIC_RELAXED, AGT);
}
static __device__ __forceinline__ void ast(unsigned* p, unsigned v) {
    __hip_atomic_store(p, v, __ATOMIC_RELAXED, AGT);
}
// ---- coherent wide VMEM (device-scope) ----
static __device__ __forceinline__ void ld16c(u16x8* d, const void* p) {
    asm volatile("global_load_dwordx4 %0, %1, off sc0 sc1"
                 : "=&v"(*d) : "v"(p) : "memory");
}
static __device__ __forceinline__ void ld8c(u16x4* d, const void* p) {
    asm volatile("global_load_dwordx2 %0, %1, off sc0 sc1"
                 : "=&v"(*d) : "v"(p) : "memory");
}
static __device__ __forceinline__ void st4c(void* p, unsigned v) {
    asm volatile("global_store_dword %0, %1, off sc0 sc1"
                 :: "v"(p), "v"(v) : "memory");
}
static __device__ __forceinline__ void wait0() {
    asm volatile("s_waitcnt vmcnt(0)" ::: "memory");
    __builtin_amdgcn_sched_barrier(0);
}
static __device__ __forceinline__ void wait2() {
    asm volatile("s_waitcnt vmcnt(2)" ::: "memory");
    __builtin_amdgcn_sched_barrier(0);
}

// ---------------------------------------------------------------------------
// One-time converts
// ---------------------------------------------------------------------------
__global__ __launch_bounds__(256) void convert_WT(
    const float* __restrict__ W, ushortT* __restrict__ WbfT,
    int K, int NG, int KP, int total)
{
    for (int idx = blockIdx.x * 256 + threadIdx.x; idx < total; idx += gridDim.x * 256) {
        const int m = idx / KP, k = idx - m * KP;
        WbfT[idx] = (k < K) ? f2bf(W[(size_t)k * NG + m]) : (ushortT)0;
    }
}
__global__ __launch_bounds__(256) void convert_emb(
    const float* __restrict__ emb, ushortT* __restrict__ embbf)
{
    const int total = VOCABN * KP0;
    for (int idx = blockIdx.x * 256 + threadIdx.x; idx < total; idx += gridDim.x * 256) {
        const int v = idx / KP0, k = idx - v * KP0;
        embbf[idx] = (k < EMB_D) ? f2bf(emb[(size_t)v * EMB_D + k]) : (ushortT)0;
    }
}

// ---------------------------------------------------------------------------
// Precompute ALL of xg0: xg0[t][g][m][b16] bf16 (no recurrence dependency).
// ---------------------------------------------------------------------------
__global__ __launch_bounds__(256) void gemm_xg0(
    const ushortT* __restrict__ embbf,
    const int*   __restrict__ tokens,
    const ushortT* __restrict__ W0T,     // [1024][KP0]
    const float* __restrict__ bias,
    ushortT* __restrict__ xg0)           // [512][8][1024][16]
{
    __shared__ ushortT Wl[128][32];
    __shared__ ushortT Xl[128][32];
    __shared__ int tokL[128];

    const int tid = threadIdx.x;
    const int t   = blockIdx.x;
    const int m0  = blockIdx.y * 128;
    const int wv  = tid >> 6;
    const int lane = tid & 63;
    const int lo  = lane & 15;
    const int hi  = lane >> 4;

    if (tid < 128) tokL[tid] = tokens[tid * SEQT + t];
    __syncthreads();

    f32x4 acc[2][8];
    #pragma unroll
    for (int s = 0; s < 2; ++s)
        #pragma unroll
        for (int n = 0; n < 8; ++n)
            acc[s][n] = f32x4{0.f, 0.f, 0.f, 0.f};

    for (int k0 = 0; k0 < KP0; k0 += 32) {
        #pragma unroll
        for (int it = 0; it < 2; ++it) {
            const int idx = tid + it * 256;
            const int row = idx >> 2, gq = idx & 3;
            const int gs  = gq ^ ((row >> 1) & 3);
            *(u16x8*)&Wl[row][gs * 8] =
                *(const u16x8*)(W0T + (size_t)(m0 + row) * KP0 + k0 + gq * 8);
            *(u16x8*)&Xl[row][gs * 8] =
                *(const u16x8*)(embbf + (size_t)tokL[row] * KP0 + k0 + gq * 8);
        }
        __syncthreads();

        bf16x8 bfr[8];
        #pragma unroll
        for (int n = 0; n < 8; ++n) {
            const int row = n * 16 + lo;
            bfr[n] = *(const bf16x8*)&Xl[row][(hi ^ ((row >> 1) & 3)) * 8];
        }
        #pragma unroll
        for (int s = 0; s < 2; ++s) {
            const int row = wv * 32 + s * 16 + lo;
            const bf16x8 a = *(const bf16x8*)&Wl[row][(hi ^ ((row >> 1) & 3)) * 8];
            #pragma unroll
            for (int n = 0; n < 8; ++n)
                acc[s][n] = __builtin_amdgcn_mfma_f32_16x16x32_bf16(a, bfr[n], acc[s][n], 0, 0, 0);
        }
        __syncthreads();
    }

    #pragma unroll
    for (int s = 0; s < 2; ++s)
        #pragma unroll
        for (int j = 0; j < 4; ++j) {
            const int m = m0 + wv * 32 + s * 16 + hi * 4 + j;
            const float bi = bias[m];
            #pragma unroll
            for (int n = 0; n < 8; ++n)
                xg0[(((size_t)t * 8 + n) * 1024 + m) * 16 + lo] = f2bf(acc[s][n][j] + bi);
        }
}

// ---------------------------------------------------------------------------
// Recurrence role, 256 thr / 4 waves. Each WAVE owns 16 h-cols and computes
// ALL 4 gates for them (4 MFMA chains) -> no LDS gate exchange, no extra
// barrier; every thread holds i,f,c,o for its (b,j) in registers. One flag
// per WG (per-wave vmcnt drain + barrier + tid0 release). Single merged poll.
// xg register-prefetched one step ahead (off critical path).
// ---------------------------------------------------------------------------
template<int U_, bool XATOMIC, int XTSH, int XPH>
__device__ void rec_role(
    int rid,
    const float* __restrict__ Umat,
    const ushortT* __restrict__ xgring, int xmask,
    ushortT* __restrict__ hring,
    unsigned* Fown,
    unsigned* Xown,
    unsigned* Xguard, int nGd,
    char* smem)
{
    constexpr int NGu = 4 * U_;
    constexpr int WPG = U_ / 64;        // WGs per group
    constexpr int KT  = U_ / 32;        // MFMA K-tiles
    constexpr int GR  = U_ / 8;         // 16B granules per h row
    constexpr int NLD = (16 * GR) / 256;

    ushortT* hstage = (ushortT*)smem;   // [16][U], swizzled granules

    const int tid = threadIdx.x, w = tid >> 6, lane = tid & 63;
    const int lo = lane & 15, hi = lane >> 4;
    const int grp = rid & 7, wgj = rid >> 3;
    const int b0 = grp * 16, J = wgj * 64;
    const int jcol = J + w * 16 + lo;   // this thread's h-column
    const size_t S = (size_t)128 * U_;

    // persistent B-fragments: all 4 gates for column jcol
    bf16x8 bfr[4][KT];
    #pragma unroll
    for (int g = 0; g < 4; ++g)
        #pragma unroll
        for (int kt = 0; kt < KT; ++kt) {
            const float* up = Umat + (size_t)(kt * 32 + hi * 8) * NGu + g * U_ + jcol;
            bf16x8 v;
            #pragma unroll
            for (int i = 0; i < 8; ++i) v[i] = (short)f2bf(up[(size_t)i * NGu]);
            bfr[g][kt] = v;
        }

    float creg[4] = {0.f, 0.f, 0.f, 0.f};

    // ---- pre-loop: xg slab 0 prefetch ----
    if (XATOMIC) {
        if (w == 0) {
            int guard = 0; bool ok;
            do {
                bool pred = true;
                if (lane < 4) {
                    const int mt = (lane * U_ + J) >> XTSH;
                    pred = ((int)ald(&Xown[(mt * XPH) * 16]) >= 1);
                }
                ok = __all(pred);
                if (!ok) __builtin_amdgcn_s_sleep(2);
            } while (!ok && ++guard < LIM);
        }
        __syncthreads();
    }
    u16x4 xnext[4];
    {
        const size_t xb = (size_t)grp * NGu;   // slab 0
        #pragma unroll
        for (int g = 0; g < 4; ++g) {
            const ushortT* ap = xgring + (xb + g * U_ + jcol) * 16 + hi * 4;
            if (XATOMIC) ld8c(&xnext[g], ap);
            else         xnext[g] = *(const u16x4*)ap;
        }
        if (XATOMIC) wait0();
    }

    for (int t = 0; t < SEQT; ++t) {
        // ---- single merged poll (wave 0) ----
        if (w == 0) {
            int guard = 0; bool ok;
            do {
                bool pred = true;
                if (t > 0 && lane < WPG)
                    pred = ((int)ald(&Fown[(grp * WPG + lane) * 16]) >= t);
                if (XATOMIC && t + 1 < SEQT && lane < 4) {
                    const int mt = (lane * U_ + J) >> XTSH;
                    const int fi = mt * XPH + ((t + 1) & (XPH - 1));
                    pred = pred && ((int)ald(&Xown[fi * 16]) >= t + 2);
                }
                for (int i = lane; i < nGd; i += 64)
                    pred = pred && ((int)ald(&Xguard[i * 16]) >= t - (RING - 1));
                ok = __all(pred);
                if (!ok) __builtin_amdgcn_s_sleep(1);
            } while (!ok && ++guard < LIM);
        }
        __syncthreads();   // B1: deps satisfied

        // xg for step t (loaded last iteration, drained by last wait0)
        u16x4 xcur[4];
        #pragma unroll
        for (int g = 0; g < 4; ++g) xcur[g] = xnext[g];

        // h stage (coherent batch), then LDS write
        u16x8 hr[NLD];
        if (t > 0) {
            const ushortT* hsrc = hring + (size_t)((t - 1) & (RING - 1)) * S;
            #pragma unroll
            for (int q = 0; q < NLD; ++q) {
                const int i = tid + q * 256;
                const int row = i / GR, gi = i - row * GR;
                ld16c(&hr[q], hsrc + (size_t)(b0 + row) * U_ + gi * 8);
            }
            wait0();
            #pragma unroll
            for (int q = 0; q < NLD; ++q) {
                const int i = tid + q * 256;
                const int row = i / GR, gi = i - row * GR;
                *(u16x8*)&hstage[(row * GR + (gi ^ (row & 7))) * 8] = hr[q];
            }
        }
        // prefetch xg[t+1] (overlaps MFMA + stores)
        if (t + 1 < SEQT) {
            const size_t xb = (size_t)(((t + 1) & xmask) * 8 + grp) * NGu;
            #pragma unroll
            for (int g = 0; g < 4; ++g) {
                const ushortT* ap = xgring + (xb + g * U_ + jcol) * 16 + hi * 4;
                if (XATOMIC) ld8c(&xnext[g], ap);
                else         xnext[g] = *(const u16x4*)ap;
            }
        }
        __syncthreads();   // B2: h staged

        // 4 gate MFMA chains
        f32x4 acc[4];
        #pragma unroll
        for (int g = 0; g < 4; ++g) acc[g] = f32x4{0.f, 0.f, 0.f, 0.f};
        if (t > 0) {
            #pragma unroll
            for (int kt = 0; kt < KT; ++kt) {
                const int gs = (kt * 4 + hi) ^ (lo & 7);
                const bf16x8 a = *(const bf16x8*)&hstage[(lo * GR + gs) * 8];
                #pragma unroll
                for (int g = 0; g < 4; ++g)
                    acc[g] = __builtin_amdgcn_mfma_f32_16x16x32_bf16(a, bfr[g][kt], acc[g], 0, 0, 0);
            }
        }

        // gates fully in-register; update c, compute h, pack, store
        ushortT* hwr = hring + (size_t)(t & (RING - 1)) * S;
        unsigned own[4], oth[4];
        #pragma unroll
        for (int r = 0; r < 4; ++r) {
            const float i_ = sigmoidf_(acc[0][r] + bf2f(xcur[0][r]));
            const float f_ = sigmoidf_(acc[1][r] + bf2f(xcur[1][r]));
            const float cc = fmaxf(acc[2][r] + bf2f(xcur[2][r]), 0.f);
            const float o_ = sigmoidf_(acc[3][r] + bf2f(xcur[3][r]));
            creg[r] = f_ * creg[r] + i_ * cc;
            own[r] = (unsigned)f2bf(o_ * fmaxf(creg[r], 0.f));
        }
        #pragma unroll
        for (int r = 0; r < 4; ++r)
            oth[r] = (unsigned)__shfl_xor((int)own[r], 1);
        {
            const int odd = lo & 1;
            const int rb = odd ? 2 : 0;
            const int je = jcol - odd;
            #pragma unroll
            for (int q = 0; q < 2; ++q) {
                const int r = rb + q;
                const unsigned pk = odd ? (oth[r] | (own[r] << 16))
                                        : (own[r] | (oth[r] << 16));
                st4c(&hwr[(size_t)(b0 + hi * 4 + r) * U_ + je], pk);
            }
        }
        wait0();           // drain own h stores (+ xg prefetch)
        __syncthreads();   // B3: all waves drained
        if (tid == 0)
            ast(&Fown[(grp * WPG + wgj) * 16], (unsigned)(t + 1));
    }
}

// ---------------------------------------------------------------------------
// GEMM worker, 256 thr / 4 waves: MC m-cols, W in LDS once, h slab via
// coherent dwordx4 with counted-vmcnt ping-pong, packed coherent stores.
// ---------------------------------------------------------------------------
template<int MC, int NGATES, int KP, int P>
__device__ void worker_role(
    int mtile, int phase,
    const ushortT* __restrict__ WT,     // [NGATES][KP] bf16
    const float* __restrict__ bias,
    const ushortT* __restrict__ hring,  // [RING][128][KP]
    ushortT* __restrict__ xgring,       // [RING][8][NGATES][16]
    unsigned* Fup, int nUp,
    unsigned* Fguard, int nGd,
    unsigned* Xrel,
    char* smem)
{
    constexpr int GR2 = KP / 8;
    constexpr int NIT = KP / 32;
    constexpr int WR  = MC / 4;          // m-cols per wave
    constexpr int MT  = WR / 16;
    ushortT* Wl = (ushortT*)smem;
    ushortT* Xl = (ushortT*)(smem + (size_t)MC * KP * 2);   // 2 x [128][32]

    const int tid = threadIdx.x, w = tid >> 6, lane = tid & 63;
    const int lo = lane & 15, hi = lane >> 4;
    const int m0 = mtile * MC;
    const int row = tid >> 1, gq0 = (tid & 1) * 2;
    const int gs0 = gq0 ^ ((row >> 1) & 3);
    const int gs1 = (gq0 + 1) ^ ((row >> 1) & 3);

    for (int i = tid; i < MC * GR2; i += 256) {
        const int r_ = i / GR2, gi = i - r_ * GR2;
        const int gs = gi ^ (r_ & 7);
        *(u16x8*)&Wl[(r_ * GR2 + gs) * 8] =
            *(const u16x8*)(WT + (size_t)(m0 + r_) * KP + gi * 8);
    }
    float bv[MT][4];
    #pragma unroll
    for (int mt = 0; mt < MT; ++mt)
        #pragma unroll
        for (int j = 0; j < 4; ++j)
            bv[mt][j] = bias[m0 + w * WR + mt * 16 + hi * 4 + j];
    __syncthreads();

    for (int t = phase; t < SEQT; t += P) {
        if (w == 0) {
            int guard = 0; bool ok;
            do {
                bool pred = true;
                for (int i = lane; i < nUp; i += 64)
                    pred = pred && ((int)ald(&Fup[i * 16]) >= t + 1);
                for (int i = lane; i < nGd; i += 64)
                    pred = pred && ((int)ald(&Fguard[i * 16]) >= t - (RING - 1));
                ok = __all(pred);
                if (!ok) __builtin_amdgcn_s_sleep(32);
            } while (!ok && ++guard < LIM);
        }
        __syncthreads();

        const ushortT* hslab = hring + (size_t)(t & (RING - 1)) * 128 * KP;

        f32x4 acc[MT][8];
        #pragma unroll
        for (int mt = 0; mt < MT; ++mt)
            #pragma unroll
            for (int nn = 0; nn < 8; ++nn) acc[mt][nn] = f32x4{0.f, 0.f, 0.f, 0.f};

        u16x8 Ra0, Ra1, Rb0, Rb1;
        ld16c(&Ra0, hslab + (size_t)row * KP + gq0 * 8);
        ld16c(&Ra1, hslab + (size_t)row * KP + (gq0 + 1) * 8);
        #pragma unroll
        for (int it = 0; it < NIT; ++it) {
            const bool even = ((it & 1) == 0);
            if (it + 1 < NIT) {
                const ushortT* np = hslab + (size_t)row * KP + (it + 1) * 32;
                if (even) { ld16c(&Rb0, np + gq0 * 8); ld16c(&Rb1, np + (gq0 + 1) * 8); }
                else      { ld16c(&Ra0, np + gq0 * 8); ld16c(&Ra1, np + (gq0 + 1) * 8); }
                wait2();
            } else {
                wait0();
            }
            ushortT* Xc = Xl + (it & 1) * (128 * 32);
            *(u16x8*)&Xc[row * 32 + gs0 * 8] = even ? Ra0 : Rb0;
            *(u16x8*)&Xc[row * 32 + gs1 * 8] = even ? Ra1 : Rb1;
            __syncthreads();
            #pragma unroll
            for (int mt = 0; mt < MT; ++mt) {
                const int arow = w * WR + mt * 16 + lo;
                const int gsa = (it * 4 + hi) ^ (arow & 7);
                const bf16x8 a = *(const bf16x8*)&Wl[(arow * GR2 + gsa) * 8];
                #pragma unroll
                for (int nn = 0; nn < 8; ++nn) {
                    const int brow = nn * 16 + lo;
                    const bf16x8 b = *(const bf16x8*)&Xc[brow * 32 + (hi ^ ((brow >> 1) & 3)) * 8];
                    acc[mt][nn] = __builtin_amdgcn_mfma_f32_16x16x32_bf16(a, b, acc[mt][nn], 0, 0, 0);
                }
            }
            __syncthreads();
        }

        const size_t slab = (size_t)(t & (RING - 1)) * 8;
        #pragma unroll
        for (int mt = 0; mt < MT; ++mt) {
            #pragma unroll
            for (int nn = 0; nn < 8; ++nn) {
                const int b = nn * 16 + lo;
                unsigned own[4], oth[4];
                #pragma unroll
                for (int j = 0; j < 4; ++j)
                    own[j] = (unsigned)f2bf(acc[mt][nn][j] + bv[mt][j]);
                #pragma unroll
                for (int j = 0; j < 4; ++j)
                    oth[j] = (unsigned)__shfl_xor((int)own[j], 1);
                const int odd = lo & 1;
                const int jb = odd ? 2 : 0;
                const int be = (b & 15) - odd;
                #pragma unroll
                for (int q = 0; q < 2; ++q) {
                    const int j = jb + q;
                    const int m = m0 + w * WR + mt * 16 + hi * 4 + j;
                    const unsigned pk = odd ? (oth[j] | (own[j] << 16))
                                            : (own[j] | (oth[j] << 16));
                    st4c(&xgring[((slab + nn) * NGATES + m) * 16 + be], pk);
                }
            }
        }
        wait0();
        __syncthreads();
        if (tid == 0)
            ast(Xrel, (unsigned)(t + 1));
    }
}

// ---------------------------------------------------------------------------
// Megakernel. Grid 224 x 256 thr, 1 WG/CU (LDS-bound).
//  [0,32) L0  [32,96) L1  [96,128) L2  [128,192) G1 (8mt x 8ph)  [192,224) G2 (8mt x 4ph)
// ---------------------------------------------------------------------------
struct MegaArgs {
    const float *U0, *U1, *U2;
    const ushortT *W1T, *W2T;
    const float *b1, *b2;
    const ushortT* xg0;
    ushortT *xg1, *xg2;
    ushortT *h0r, *h1r, *h2r;
    unsigned *F0, *F1, *F2, *X1, *X2;
};

__global__ __launch_bounds__(256, 1) void mega(MegaArgs A)
{
    extern __shared__ char smem[];
    const int bid = blockIdx.x;
    if (bid < 32) {
        rec_role<NU0, false, 1, 1>(bid, A.U0, A.xg0, 511, A.h0r, A.F0,
                                   nullptr, A.X1, 64, smem);
    } else if (bid < 96) {
        rec_role<NU1, true, 8, 8>(bid - 32, A.U1, A.xg1, RING - 1, A.h1r, A.F1,
                                  A.X1, A.X2, 32, smem);
    } else if (bid < 128) {
        rec_role<NU2, true, 7, 4>(bid - 96, A.U2, A.xg2, RING - 1, A.h2r, A.F2,
                                  A.X2, nullptr, 0, smem);
    } else if (bid < 192) {
        const int wid = bid - 128;
        const int mt = wid & 7, ph = wid >> 3;     // 8 mtiles x 8 phases
        worker_role<256, 2048, 256, 8>(mt, ph, A.W1T, A.b1, A.h0r, A.xg1,
                                       A.F0, 32, A.F1, 64, A.X1 + (mt * 8 + ph) * 16, smem);
    } else {
        const int wid = bid - 192;
        const int mt = wid & 7, ph = wid >> 3;     // 8 mtiles x 4 phases
        worker_role<128, 1024, 512, 4>(mt, ph, A.W2T, A.b2, A.h1r, A.xg2,
                                       A.F1, 64, A.F2, 32, A.X2 + (mt * 4 + ph) * 16, smem);
    }
}

// ---------------------------------------------------------------------------
// Head
// ---------------------------------------------------------------------------
__global__ __launch_bounds__(64) void head_kernel(
    const ushortT* __restrict__ h2,
    const float* __restrict__ Wd,
    const float* __restrict__ bd,
    const float* __restrict__ Wc,
    const float* __restrict__ bc,
    float* __restrict__ out)
{
    const int b = blockIdx.x;
    const int j = threadIdx.x;
    float a = bd[j];
    const ushortT* hrow = h2 + (size_t)b * NU2;
    #pragma unroll 4
    for (int k = 0; k < NU2; ++k)
        a += bf2f(hrow[k]) * Wd[(size_t)k * NDENSE + j];
    a = fmaxf(a, 0.f) * Wc[j];
    #pragma unroll
    for (int off = 32; off > 0; off >>= 1)
        a += __shfl_down(a, off);
    if (j == 0)
        out[b] = 1.f / (1.f + expf(-(a + bc[0])));
}

// ---------------------------------------------------------------------------
extern "C" void kernel_launch(void* const* d_in, const int* in_sizes, int n_in,
                              void* d_out, int out_size, void* d_ws, size_t ws_size,
                              hipStream_t stream)
{
    const int*   tokens = (const int*)  d_in[0];
    const float* emb    = (const float*)d_in[1];
    const float* W0     = (const float*)d_in[2];
    const float* Ur0    = (const float*)d_in[3];
    const float* b0v    = (const float*)d_in[4];
    const float* W1     = (const float*)d_in[5];
    const float* Ur1    = (const float*)d_in[6];
    const float* b1v    = (const float*)d_in[7];
    const float* W2     = (const float*)d_in[8];
    const float* Ur2    = (const float*)d_in[9];
    const float* b2v    = (const float*)d_in[10];
    const float* Wd     = (const float*)d_in[11];
    const float* bd     = (const float*)d_in[12];
    const float* Wc     = (const float*)d_in[13];
    const float* bc     = (const float*)d_in[14];
    float* out = (float*)d_out;

    char* p = (char*)d_ws;
    auto alloc = [&](size_t bytes) -> char* {
        char* q = p; p += (bytes + 255) & ~(size_t)255; return q;
    };
    ushortT* xg0   = (ushortT*)alloc((size_t)SEQT * 8 * 1024 * 16 * 2);  // 128 MB
    ushortT* xg1   = (ushortT*)alloc((size_t)RING * 8 * 2048 * 16 * 2);  // 16 MB
    ushortT* xg2   = (ushortT*)alloc((size_t)RING * 8 * 1024 * 16 * 2);  // 8 MB
    ushortT* h0r   = (ushortT*)alloc((size_t)RING * 128 * NU0 * 2);
    ushortT* h1r   = (ushortT*)alloc((size_t)RING * 128 * NU1 * 2);
    ushortT* h2r   = (ushortT*)alloc((size_t)RING * 128 * NU2 * 2);
    ushortT* W0T   = (ushortT*)alloc((size_t)1024 * KP0 * 2);
    ushortT* W1T   = (ushortT*)alloc((size_t)2048 * NU0 * 2);
    ushortT* W2T   = (ushortT*)alloc((size_t)1024 * NU1 * 2);
    ushortT* embbf = (ushortT*)alloc((size_t)VOCABN * KP0 * 2);
    unsigned* flg  = (unsigned*)alloc(32768);

    // flag partition (16-word stride), one flag per WG / worker tile-phase
    unsigned* F0 = flg;             // 32  (L0 WGs: grp*4+wgj)
    unsigned* F1 = F0 + 32 * 16;    // 64  (L1 WGs: grp*8+wgj)
    unsigned* F2 = F1 + 64 * 16;    // 32  (L2 WGs: grp*4+wgj)
    unsigned* X1 = F2 + 32 * 16;    // 64  (8 G1 mtiles x 8 phases)
    unsigned* X2 = X1 + 64 * 16;    // 32  (8 G2 mtiles x 4 phases)

    hipMemsetAsync(flg, 0, 32768, stream);

    convert_WT<<<512, 256, 0, stream>>>(W0, W0T, EMB_D, 1024, KP0, 1024 * KP0);
    convert_WT<<<512, 256, 0, stream>>>(W1, W1T, NU0, 2048, NU0, 2048 * NU0);
    convert_WT<<<512, 256, 0, stream>>>(W2, W2T, NU1, 1024, NU1, 1024 * NU1);
    convert_emb<<<1024, 256, 0, stream>>>(emb, embbf);

    gemm_xg0<<<dim3(SEQT, 8), 256, 0, stream>>>(embbf, tokens, W0T, b0v, xg0);

    MegaArgs A;
    A.U0 = Ur0; A.U1 = Ur1; A.U2 = Ur2;
    A.W1T = W1T; A.W2T = W2T;
    A.b1 = b1v; A.b2 = b2v;
    A.xg0 = xg0; A.xg1 = xg1; A.xg2 = xg2;
    A.h0r = h0r; A.h1r = h1r; A.h2r = h2r;
    A.F0 = F0; A.F1 = F1; A.F2 = F2; A.X1 = X1; A.X2 = X2;

    void* args[] = {&A};
    // smem: worker max = MC*KP*2 (131072) + 2*128*32*2 (16384) = 147456
    hipLaunchCooperativeKernel((void*)mega, dim3(224), dim3(256), args, 147456, stream);

    // final h of layer 2 = ring slab (511 & 31) = 31
    head_kernel<<<BATCH, 64, 0, stream>>>(h2r + (size_t)31 * 128 * NU2,
                                          Wd, bd, Wc, bc, out);
}